// Round 3
// baseline (848.128 us; speedup 1.0000x reference)
//
#include <hip/hip_runtime.h>

#define TOKENS 2048
#define HD 1024
#define NEXP 16
#define TWO_I 4096
#define ID 2048

typedef short short8 __attribute__((ext_vector_type(8)));
typedef float f32x4 __attribute__((ext_vector_type(4)));
typedef unsigned short ushort;

static __device__ __forceinline__ ushort f2bf(float f) {
    union { float f; unsigned u; } v; v.f = f;
    unsigned r = v.u + 0x7FFFu + ((v.u >> 16) & 1u);
    return (ushort)(r >> 16);
}

static __device__ __forceinline__ void gload_lds16(const void* g, void* l) {
    __builtin_amdgcn_global_load_lds(
        (const __attribute__((address_space(1))) unsigned int*)(g),
        (__attribute__((address_space(3))) unsigned int*)(l), 16, 0, 0);
}

// ---------------- hidden fp32 -> bf16 ----------------
__global__ __launch_bounds__(256) void cvt_kernel(const float* __restrict__ hs,
                                                  ushort* __restrict__ hb) {
    int i = (blockIdx.x * 256 + threadIdx.x) * 4;
    float4 v = *(const float4*)(hs + i);
    union { ushort b[4]; float2 f2; } u;
    u.b[0] = f2bf(v.x); u.b[1] = f2bf(v.y); u.b[2] = f2bf(v.z); u.b[3] = f2bf(v.w);
    *(float2*)(hb + i) = u.f2;
}

// ---------------- weight transpose+convert: [E][K][N] f32 -> [E][N][K] bf16 ----
__global__ __launch_bounds__(256) void transpose_cvt_kernel(
    const float* __restrict__ src, ushort* __restrict__ dst, int K, int N) {
    const int e = blockIdx.z;
    const int n0 = blockIdx.x * 64;
    const int k0 = blockIdx.y * 64;
    __shared__ float T[64][68];
    const float* s = src + (size_t)e * K * N + (size_t)k0 * N + n0;
    const int r = threadIdx.x >> 4;
    const int c4 = (threadIdx.x & 15) * 4;
#pragma unroll
    for (int i = 0; i < 64; i += 16) {
        float4 v = *(const float4*)(s + (size_t)(r + i) * N + c4);
        T[r + i][c4 + 0] = v.x; T[r + i][c4 + 1] = v.y;
        T[r + i][c4 + 2] = v.z; T[r + i][c4 + 3] = v.w;
    }
    __syncthreads();
    const int n = threadIdx.x >> 2;
    const int kc = (threadIdx.x & 3) * 16;
    union { ushort b[16]; short8 v[2]; } o;
#pragma unroll
    for (int j = 0; j < 16; ++j) o.b[j] = f2bf(T[kc + j][n]);
    ushort* d = dst + (size_t)e * N * K + (size_t)(n0 + n) * K + k0 + kc;
    *(short8*)(d) = o.v[0];
    *(short8*)(d + 8) = o.v[1];
}

// ---------------- router: logits -> softmax -> top4 -> renorm ----------------
__global__ __launch_bounds__(256) void router_kernel(
    const float* __restrict__ hs, const float* __restrict__ rw,
    const float* __restrict__ rb, float* __restrict__ topk_w_out,
    int* __restrict__ topk_idx, int* __restrict__ counts) {
    const int wave = threadIdx.x >> 6;
    const int lane = threadIdx.x & 63;
    const int t = blockIdx.x * 4 + wave;

    float h[16];
#pragma unroll
    for (int j = 0; j < 16; ++j) h[j] = hs[t * HD + j * 64 + lane];

    __shared__ float lg[4][NEXP];
#pragma unroll
    for (int e = 0; e < NEXP; ++e) {
        float acc = 0.f;
#pragma unroll
        for (int j = 0; j < 16; ++j) acc += h[j] * rw[e * HD + j * 64 + lane];
#pragma unroll
        for (int s = 32; s > 0; s >>= 1) acc += __shfl_xor(acc, s);
        if (lane == 0) lg[wave][e] = acc + rb[e];
    }
    if (lane == 0) {
        float mx = lg[wave][0];
        for (int e = 1; e < NEXP; ++e) mx = fmaxf(mx, lg[wave][e]);
        float pr[NEXP];
        for (int e = 0; e < NEXP; ++e) pr[e] = __expf(lg[wave][e] - mx);
        int idx[4]; float wv[4]; float sum4 = 0.f;
        for (int k = 0; k < 4; ++k) {
            int bi = 0; float bv = -1.f;
            for (int e = 0; e < NEXP; ++e)
                if (pr[e] > bv) { bv = pr[e]; bi = e; }
            idx[k] = bi; wv[k] = bv; pr[bi] = -2.f; sum4 += bv;
        }
        for (int k = 0; k < 4; ++k) {
            topk_w_out[t * 4 + k] = wv[k] / sum4;
            topk_idx[t * 4 + k] = idx[k];
            atomicAdd(&counts[idx[k]], 1);
        }
    }
}

// ---------------- prefix scan over 16 counts ----------------
__global__ void scan_kernel(const int* __restrict__ counts, int* __restrict__ offsets,
                            int* __restrict__ cursor) {
    if (threadIdx.x == 0 && blockIdx.x == 0) {
        int o = 0;
        for (int e = 0; e < NEXP; ++e) { offsets[e] = o; cursor[e] = o; o += counts[e]; }
        offsets[NEXP] = o;
    }
}

// ---------------- build per-expert token lists ----------------
__global__ __launch_bounds__(256) void build_kernel(
    const int* __restrict__ topk_idx, const float* __restrict__ topk_w,
    int* __restrict__ cursor, int* __restrict__ token_list, float* __restrict__ slot_w,
    int* __restrict__ slot_of) {
    int t = blockIdx.x * 256 + threadIdx.x;
    for (int k = 0; k < 4; ++k) {
        int e = topk_idx[t * 4 + k];
        int pos = atomicAdd(&cursor[e], 1);
        token_list[pos] = t;
        slot_w[pos] = topk_w[t * 4 + k];
        slot_of[t * 4 + k] = pos;
    }
}

// ============ grouped 128x128 GEMMs: XOR-swizzled LDS + counted-vmcnt pipeline ====
//
// LDS layout [128 rows][32 ushorts] (64B rows). Linear layout has an ~4-way bank
// conflict on ds_read_b128 (rows m, m+2 alias). Swizzle: data for k-slot s is
// stored at 16B-slot s^(row&3). global_load_lds writes linearly (lane*16B), so
// the swizzle is applied to the per-lane GLOBAL source column (rule: linear dest
// + inverse-swizzled source + swizzled read). Read slot q^(m&3) is a per-thread
// constant -> zero loop overhead. Verified uniform: 8 lanes per 4-bank group.

// ---- GEMM1: act[slot][I] = GLU((hb[tok] . gupT[e]) + bias) ----
__global__ __launch_bounds__(256) void gemm1_t_kernel(
    const ushort* __restrict__ hb, const ushort* __restrict__ gupT,
    const float* __restrict__ gub, const int* __restrict__ offsets,
    const int* __restrict__ token_list, ushort* __restrict__ act) {
    const int e = blockIdx.z;
    const int so = offsets[e];
    const int ne = offsets[e + 1] - so;
    const int row0 = blockIdx.y * 128;
    if (row0 >= ne) return;
    const int n0 = blockIdx.x * 128;

    __shared__ ushort As[2][4096];
    __shared__ ushort Bs[2][4096];

    const int tid = threadIdx.x;
    const int lane = tid & 63;
    const int w = tid >> 6;
    const int m = lane & 15;
    const int q = lane >> 4;
    const int wm = (w >> 1) * 64;
    const int wn = (w & 1) * 64;
    const int qa = (q ^ (m & 3)) * 8;      // swizzled read slot (constant per thread)

    const int r0 = tid >> 2;
    // swizzled source column: slot (tid&3) at row r0 holds k-chunk (tid&3)^(r0&3)
    const int ce = (((tid & 3) ^ (r0 & 3)) * 8);
    int ar0 = row0 + r0;       if (ar0 >= ne) ar0 = ne - 1;
    int ar1 = row0 + 64 + r0;  if (ar1 >= ne) ar1 = ne - 1;
    const ushort* ga0 = hb + (size_t)token_list[so + ar0] * HD + ce;
    const ushort* ga1 = hb + (size_t)token_list[so + ar1] * HD + ce;
    const ushort* gb0 = gupT + (size_t)e * TWO_I * HD + (size_t)(n0 + r0) * HD + ce;
    const ushort* gb1 = gb0 + (size_t)64 * HD;

    f32x4 acc[4][4] = {};

#define STAGE1(B, K0) do { \
    gload_lds16(ga0 + (K0), As[B] + w * 512); \
    gload_lds16(ga1 + (K0), As[B] + 2048 + w * 512); \
    gload_lds16(gb0 + (K0), Bs[B] + w * 512); \
    gload_lds16(gb1 + (K0), Bs[B] + 2048 + w * 512); \
} while (0)

#define COMPUTE1(B) do { \
    short8 af[4], bfr[4]; \
    _Pragma("unroll") for (int rt = 0; rt < 4; ++rt) \
        af[rt] = *(const short8*)(As[B] + (wm + rt * 16 + m) * 32 + qa); \
    _Pragma("unroll") for (int c = 0; c < 4; ++c) \
        bfr[c] = *(const short8*)(Bs[B] + (wn + c * 16 + m) * 32 + qa); \
    _Pragma("unroll") for (int rt = 0; rt < 4; ++rt) \
        _Pragma("unroll") for (int c = 0; c < 4; ++c) \
            acc[rt][c] = __builtin_amdgcn_mfma_f32_16x16x32_bf16(af[rt], bfr[c], acc[rt][c], 0, 0, 0); \
} while (0)

    STAGE1(0, 0);                                   // tile 0 in flight (4 loads)
    int cur = 0;
    for (int t = 0; t < HD / 32 - 1; ++t) {
        STAGE1(cur ^ 1, (t + 1) * 32);              // tile t+1 in flight (8 total)
        asm volatile("s_waitcnt vmcnt(4)" ::: "memory");  // tile t landed (this wave)
        __builtin_amdgcn_s_barrier();               // all waves' tile t landed
        __builtin_amdgcn_s_setprio(1);
        COMPUTE1(cur);
        __builtin_amdgcn_s_setprio(0);
        __builtin_amdgcn_s_barrier();               // buf cur free for reuse
        cur ^= 1;
    }
    asm volatile("s_waitcnt vmcnt(0)" ::: "memory");
    __builtin_amdgcn_s_barrier();
    COMPUTE1(cur);                                   // last tile

#pragma unroll
    for (int c = 0; c < 4; ++c) {
        const int n = n0 + wn + c * 16 + m;
        const float bias = gub[e * TWO_I + n];
#pragma unroll
        for (int rt = 0; rt < 4; ++rt) {
#pragma unroll
            for (int rr = 0; rr < 4; ++rr) {
                const int grow = row0 + wm + rt * 16 + q * 4 + rr;
                float v = acc[rt][c][rr] + bias;
                float pv = __shfl_xor(v, 1);
                float gate = (m & 1) ? pv : v;
                float up   = (m & 1) ? v : pv;
                gate = fminf(gate, 7.0f);
                up = fminf(fmaxf(up, -7.0f), 7.0f);
                float glu = gate / (1.0f + __expf(-1.702f * gate));
                float a = (up + 1.0f) * glu;
                if (!(m & 1) && grow < ne)
                    act[(size_t)(so + grow) * ID + (n >> 1)] = f2bf(a);
            }
        }
    }
}

// ---- GEMM2: dslot[slot][H] = act[slot] . downT[e]  (raw fp32, no bias/weight) ----
__global__ __launch_bounds__(256) void gemm2_t_kernel(
    const ushort* __restrict__ act, const ushort* __restrict__ downT,
    const int* __restrict__ offsets, float* __restrict__ dslot) {
    const int e = blockIdx.z;
    const int so = offsets[e];
    const int ne = offsets[e + 1] - so;
    const int row0 = blockIdx.y * 128;
    if (row0 >= ne) return;
    const int n0 = blockIdx.x * 128;

    __shared__ ushort As[2][4096];
    __shared__ ushort Bs[2][4096];

    const int tid = threadIdx.x;
    const int lane = tid & 63;
    const int w = tid >> 6;
    const int m = lane & 15;
    const int q = lane >> 4;
    const int wm = (w >> 1) * 64;
    const int wn = (w & 1) * 64;
    const int qa = (q ^ (m & 3)) * 8;

    const int r0 = tid >> 2;
    const int ce = (((tid & 3) ^ (r0 & 3)) * 8);
    // A rows (slots) are contiguous per expert; act has 128 rows of slack.
    const ushort* ga0 = act + (size_t)(so + row0 + r0) * ID + ce;
    const ushort* ga1 = ga0 + (size_t)64 * ID;
    const ushort* gb0 = downT + (size_t)e * HD * ID + (size_t)(n0 + r0) * ID + ce;
    const ushort* gb1 = gb0 + (size_t)64 * ID;

    f32x4 acc[4][4] = {};

#define STAGE2(B, K0) do { \
    gload_lds16(ga0 + (K0), As[B] + w * 512); \
    gload_lds16(ga1 + (K0), As[B] + 2048 + w * 512); \
    gload_lds16(gb0 + (K0), Bs[B] + w * 512); \
    gload_lds16(gb1 + (K0), Bs[B] + 2048 + w * 512); \
} while (0)

#define COMPUTE2(B) do { \
    short8 af[4], bfr[4]; \
    _Pragma("unroll") for (int rt = 0; rt < 4; ++rt) \
        af[rt] = *(const short8*)(As[B] + (wm + rt * 16 + m) * 32 + qa); \
    _Pragma("unroll") for (int c = 0; c < 4; ++c) \
        bfr[c] = *(const short8*)(Bs[B] + (wn + c * 16 + m) * 32 + qa); \
    _Pragma("unroll") for (int rt = 0; rt < 4; ++rt) \
        _Pragma("unroll") for (int c = 0; c < 4; ++c) \
            acc[rt][c] = __builtin_amdgcn_mfma_f32_16x16x32_bf16(af[rt], bfr[c], acc[rt][c], 0, 0, 0); \
} while (0)

    STAGE2(0, 0);
    int cur = 0;
    for (int t = 0; t < ID / 32 - 1; ++t) {
        STAGE2(cur ^ 1, (t + 1) * 32);
        asm volatile("s_waitcnt vmcnt(4)" ::: "memory");
        __builtin_amdgcn_s_barrier();
        __builtin_amdgcn_s_setprio(1);
        COMPUTE2(cur);
        __builtin_amdgcn_s_setprio(0);
        __builtin_amdgcn_s_barrier();
        cur ^= 1;
    }
    asm volatile("s_waitcnt vmcnt(0)" ::: "memory");
    __builtin_amdgcn_s_barrier();
    COMPUTE2(cur);

    // plain coalesced fp32 stores — no atomics, no bias/weight (combine does it)
#pragma unroll
    for (int rt = 0; rt < 4; ++rt) {
#pragma unroll
        for (int rr = 0; rr < 4; ++rr) {
            const int grow = row0 + wm + rt * 16 + q * 4 + rr;
            if (grow < ne) {
                float* dp = dslot + (size_t)(so + grow) * HD + n0 + wn + m;
#pragma unroll
                for (int c = 0; c < 4; ++c) dp[c * 16] = acc[rt][c][rr];
            }
        }
    }
}

// ---- combine: out[t] = sum_k w_k * (dslot[slot_k] + bias[e_k]) ----
__global__ __launch_bounds__(256) void combine_kernel(
    const float* __restrict__ dslot, const float* __restrict__ dwb,
    const int* __restrict__ topk_idx, const int* __restrict__ slot_of,
    const float* __restrict__ topk_w, float* __restrict__ out) {
    const int t = blockIdx.x;
    const int n = threadIdx.x * 4;
    float4 o = {0.f, 0.f, 0.f, 0.f};
#pragma unroll
    for (int k = 0; k < 4; ++k) {
        const int e = topk_idx[t * 4 + k];
        const int s = slot_of[t * 4 + k];
        const float wgt = topk_w[t * 4 + k];
        float4 d = *(const float4*)(dslot + (size_t)s * HD + n);
        float4 b = *(const float4*)(dwb + (size_t)e * HD + n);
        o.x += wgt * (d.x + b.x);
        o.y += wgt * (d.y + b.y);
        o.z += wgt * (d.z + b.z);
        o.w += wgt * (d.w + b.w);
    }
    *(float4*)(out + (size_t)t * HD + n) = o;
}

// ============ FALLBACK PATH (used only if ws too small) ============

__global__ __launch_bounds__(256) void gemm1_fb_kernel(
    const ushort* __restrict__ hb, const float* __restrict__ gup,
    const float* __restrict__ gub, const int* __restrict__ offsets,
    const int* __restrict__ token_list, ushort* __restrict__ act) {
    const int e = blockIdx.z;
    const int so = offsets[e];
    const int ne = offsets[e + 1] - so;
    const int row0 = blockIdx.y * 64;
    if (row0 >= ne) return;
    const int n0 = blockIdx.x * 64;
    __shared__ ushort Al[64][40];
    __shared__ ushort Bt[64][40];
    const int tid = threadIdx.x;
    const int lane = tid & 63;
    const int wave = tid >> 6;
    const int m = lane & 15;
    const int q = lane >> 4;
    const int ar = tid >> 2;
    const int ac = (tid & 3) * 8;
    int arow = row0 + ar; if (arow >= ne) arow = ne - 1;
    const int tok = token_list[so + arow];
    const ushort* aptr = hb + tok * HD + ac;
    const int bk = tid >> 3;
    const int bn = (tid & 7) * 8;
    const float* bptr = gup + (size_t)e * HD * TWO_I + (size_t)bk * TWO_I + n0 + bn;
    f32x4 acc[4] = {{0,0,0,0},{0,0,0,0},{0,0,0,0},{0,0,0,0}};
    for (int k0 = 0; k0 < HD; k0 += 32) {
        float4 av = *(const float4*)(aptr + k0);
        *(float4*)(&Al[ar][ac]) = av;
        const float* bp = bptr + (size_t)k0 * TWO_I;
        float4 b0 = *(const float4*)(bp);
        float4 b1 = *(const float4*)(bp + 4);
        Bt[bn + 0][bk] = f2bf(b0.x); Bt[bn + 1][bk] = f2bf(b0.y);
        Bt[bn + 2][bk] = f2bf(b0.z); Bt[bn + 3][bk] = f2bf(b0.w);
        Bt[bn + 4][bk] = f2bf(b1.x); Bt[bn + 5][bk] = f2bf(b1.y);
        Bt[bn + 6][bk] = f2bf(b1.z); Bt[bn + 7][bk] = f2bf(b1.w);
        __syncthreads();
        short8 af = *(const short8*)(&Al[wave * 16 + m][q * 8]);
#pragma unroll
        for (int c = 0; c < 4; ++c) {
            short8 bf = *(const short8*)(&Bt[c * 16 + m][q * 8]);
            acc[c] = __builtin_amdgcn_mfma_f32_16x16x32_bf16(af, bf, acc[c], 0, 0, 0);
        }
        __syncthreads();
    }
#pragma unroll
    for (int c = 0; c < 4; ++c) {
        const int n = n0 + c * 16 + m;
        const float bias = gub[e * TWO_I + n];
#pragma unroll
        for (int r = 0; r < 4; ++r) {
            const int grow = row0 + wave * 16 + q * 4 + r;
            float v = acc[c][r] + bias;
            float pv = __shfl_xor(v, 1);
            float gate = (m & 1) ? pv : v;
            float up   = (m & 1) ? v : pv;
            gate = fminf(gate, 7.0f);
            up = fminf(fmaxf(up, -7.0f), 7.0f);
            float glu = gate / (1.0f + __expf(-1.702f * gate));
            float a = (up + 1.0f) * glu;
            if (!(m & 1) && grow < ne)
                act[(size_t)(so + grow) * ID + (n >> 1)] = f2bf(a);
        }
    }
}

__global__ __launch_bounds__(256) void gemm2_fb_kernel(
    const ushort* __restrict__ act, const float* __restrict__ dwp,
    const float* __restrict__ dwb, const int* __restrict__ offsets,
    const int* __restrict__ token_list, const float* __restrict__ slot_w,
    float* __restrict__ out) {
    const int e = blockIdx.z;
    const int so = offsets[e];
    const int ne = offsets[e + 1] - so;
    const int row0 = blockIdx.y * 64;
    if (row0 >= ne) return;
    const int n0 = blockIdx.x * 64;
    __shared__ ushort Al[64][40];
    __shared__ ushort Bt[64][40];
    const int tid = threadIdx.x;
    const int lane = tid & 63;
    const int wave = tid >> 6;
    const int m = lane & 15;
    const int q = lane >> 4;
    const int ar = tid >> 2;
    const int ac = (tid & 3) * 8;
    int arow = row0 + ar; if (arow >= ne) arow = ne - 1;
    const ushort* aptr = act + (size_t)(so + arow) * ID + ac;
    const int bk = tid >> 3;
    const int bn = (tid & 7) * 8;
    const float* bptr = dwp + (size_t)e * ID * HD + (size_t)bk * HD + n0 + bn;
    f32x4 acc[4] = {{0,0,0,0},{0,0,0,0},{0,0,0,0},{0,0,0,0}};
    for (int k0 = 0; k0 < ID; k0 += 32) {
        float4 av = *(const float4*)(aptr + k0);
        *(float4*)(&Al[ar][ac]) = av;
        const float* bp = bptr + (size_t)k0 * HD;
        float4 b0 = *(const float4*)(bp);
        float4 b1 = *(const float4*)(bp + 4);
        Bt[bn + 0][bk] = f2bf(b0.x); Bt[bn + 1][bk] = f2bf(b0.y);
        Bt[bn + 2][bk] = f2bf(b0.z); Bt[bn + 3][bk] = f2bf(b0.w);
        Bt[bn + 4][bk] = f2bf(b1.x); Bt[bn + 5][bk] = f2bf(b1.y);
        Bt[bn + 6][bk] = f2bf(b1.z); Bt[bn + 7][bk] = f2bf(b1.w);
        __syncthreads();
        short8 af = *(const short8*)(&Al[wave * 16 + m][q * 8]);
#pragma unroll
        for (int c = 0; c < 4; ++c) {
            short8 bf = *(const short8*)(&Bt[c * 16 + m][q * 8]);
            acc[c] = __builtin_amdgcn_mfma_f32_16x16x32_bf16(af, bf, acc[c], 0, 0, 0);
        }
        __syncthreads();
    }
#pragma unroll
    for (int r = 0; r < 4; ++r) {
        const int grow = row0 + wave * 16 + q * 4 + r;
        if (grow < ne) {
            const int slot = so + grow;
            const int tok = token_list[slot];
            const float wgt = slot_w[slot];
#pragma unroll
            for (int c = 0; c < 4; ++c) {
                const int n = n0 + c * 16 + m;
                atomicAdd(&out[tok * HD + n], (acc[c][r] + dwb[e * HD + n]) * wgt);
            }
        }
    }
}

extern "C" void kernel_launch(void* const* d_in, const int* in_sizes, int n_in,
                              void* d_out, int out_size, void* d_ws, size_t ws_size,
                              hipStream_t stream) {
    const float* hs  = (const float*)d_in[0];
    const float* rw  = (const float*)d_in[1];
    const float* rb  = (const float*)d_in[2];
    const float* gup = (const float*)d_in[3];
    const float* gub = (const float*)d_in[4];
    const float* dwp = (const float*)d_in[5];
    const float* dwb = (const float*)d_in[6];

    float* out = (float*)d_out;                       // [2048,1024] fp32
    float* topk_w = out + (size_t)TOKENS * HD;        // [2048,4] fp32

    char* w = (char*)d_ws;
    int* counts     = (int*)(w + 0);
    int* cursor     = (int*)(w + 64);
    int* offsets    = (int*)(w + 128);
    int* token_list = (int*)(w + 256);
    float* slot_w   = (float*)(w + 256 + 32768);
    int* topk_idx   = (int*)(w + 256 + 65536);
    int* slot_of    = (int*)(w + 256 + 98304);
    ushort* hb      = (ushort*)(w + ((size_t)1 << 20));           // 4 MB
    ushort* act     = (ushort*)(w + ((size_t)6 << 20));           // 8320x2048 bf16 (~34MB)
    ushort* gupT    = (ushort*)(w + ((size_t)41 << 20));          // 128 MB
    ushort* downT   = (ushort*)(w + ((size_t)169 << 20));         // 64 MB
    float* dslot    = (float*)(w + ((size_t)233 << 20));          // 8192x1024 fp32 (32 MB)
    const size_t need = (size_t)266 << 20;

    hipMemsetAsync(w, 0, 256, stream);

    cvt_kernel<<<2048, 256, 0, stream>>>(hs, hb);
    router_kernel<<<512, 256, 0, stream>>>(hs, rw, rb, topk_w, topk_idx, counts);
    scan_kernel<<<1, 64, 0, stream>>>(counts, offsets, cursor);
    build_kernel<<<8, 256, 0, stream>>>(topk_idx, topk_w, cursor, token_list, slot_w, slot_of);

    if (ws_size >= need) {
        transpose_cvt_kernel<<<dim3(TWO_I / 64, HD / 64, NEXP), 256, 0, stream>>>(
            gup, gupT, HD, TWO_I);
        transpose_cvt_kernel<<<dim3(HD / 64, ID / 64, NEXP), 256, 0, stream>>>(
            dwp, downT, ID, HD);
        gemm1_t_kernel<<<dim3(TWO_I / 128, TOKENS / 128, NEXP), 256, 0, stream>>>(
            hb, gupT, gub, offsets, token_list, act);
        gemm2_t_kernel<<<dim3(HD / 128, TOKENS / 128, NEXP), 256, 0, stream>>>(
            act, downT, offsets, dslot);
        combine_kernel<<<TOKENS, 256, 0, stream>>>(dslot, dwb, topk_idx, slot_of, topk_w, out);
    } else {
        // fallback: fp32 weights converted in-tile; atomic accumulate into zeroed out
        hipMemsetAsync(out, 0, (size_t)TOKENS * HD * sizeof(float), stream);
        gemm1_fb_kernel<<<dim3(TWO_I / 64, TOKENS / 64, NEXP), 256, 0, stream>>>(
            hb, gup, gub, offsets, token_list, act);
        gemm2_fb_kernel<<<dim3(HD / 64, TOKENS / 64, NEXP), 256, 0, stream>>>(
            act, dwp, dwb, offsets, token_list, slot_w, out);
    }
}

// Round 4
// 805.225 us; speedup vs baseline: 1.0533x; 1.0533x over previous
//
#include <hip/hip_runtime.h>

#define TOKENS 2048
#define HD 1024
#define NEXP 16
#define TWO_I 4096
#define ID 2048

typedef short short8 __attribute__((ext_vector_type(8)));
typedef float f32x4 __attribute__((ext_vector_type(4)));
typedef unsigned short ushort;

static __device__ __forceinline__ ushort f2bf(float f) {
    union { float f; unsigned u; } v; v.f = f;
    unsigned r = v.u + 0x7FFFu + ((v.u >> 16) & 1u);
    return (ushort)(r >> 16);
}

static __device__ __forceinline__ void gload_lds16(const void* g, void* l) {
    __builtin_amdgcn_global_load_lds(
        (const __attribute__((address_space(1))) unsigned int*)(g),
        (__attribute__((address_space(3))) unsigned int*)(l), 16, 0, 0);
}

// ---------------- router (+ fused hidden fp32->bf16 convert) ----------------
__global__ __launch_bounds__(256) void router_kernel(
    const float* __restrict__ hs, const float* __restrict__ rw,
    const float* __restrict__ rb, float* __restrict__ topk_w_out,
    int* __restrict__ topk_idx, int* __restrict__ counts,
    ushort* __restrict__ hb) {
    // fused convert: this block's 4 tokens = 4096 floats, 16 per thread
    {
        const int i = blockIdx.x * 4096 + threadIdx.x * 16;
#pragma unroll
        for (int j = 0; j < 4; ++j) {
            float4 v = *(const float4*)(hs + i + j * 4);
            union { ushort b[4]; float2 f2; } u;
            u.b[0] = f2bf(v.x); u.b[1] = f2bf(v.y);
            u.b[2] = f2bf(v.z); u.b[3] = f2bf(v.w);
            *(float2*)(hb + i + j * 4) = u.f2;
        }
    }

    const int wave = threadIdx.x >> 6;
    const int lane = threadIdx.x & 63;
    const int t = blockIdx.x * 4 + wave;

    float h[16];
#pragma unroll
    for (int j = 0; j < 16; ++j) h[j] = hs[t * HD + j * 64 + lane];

    __shared__ float lg[4][NEXP];
#pragma unroll
    for (int e = 0; e < NEXP; ++e) {
        float acc = 0.f;
#pragma unroll
        for (int j = 0; j < 16; ++j) acc += h[j] * rw[e * HD + j * 64 + lane];
#pragma unroll
        for (int s = 32; s > 0; s >>= 1) acc += __shfl_xor(acc, s);
        if (lane == 0) lg[wave][e] = acc + rb[e];
    }
    if (lane == 0) {
        float mx = lg[wave][0];
        for (int e = 1; e < NEXP; ++e) mx = fmaxf(mx, lg[wave][e]);
        float pr[NEXP];
        for (int e = 0; e < NEXP; ++e) pr[e] = __expf(lg[wave][e] - mx);
        int idx[4]; float wv[4]; float sum4 = 0.f;
        for (int k = 0; k < 4; ++k) {
            int bi = 0; float bv = -1.f;
            for (int e = 0; e < NEXP; ++e)
                if (pr[e] > bv) { bv = pr[e]; bi = e; }
            idx[k] = bi; wv[k] = bv; pr[bi] = -2.f; sum4 += bv;
        }
        for (int k = 0; k < 4; ++k) {
            topk_w_out[t * 4 + k] = wv[k] / sum4;
            topk_idx[t * 4 + k] = idx[k];
            atomicAdd(&counts[idx[k]], 1);
        }
    }
}

// ---------------- fused scan + build (single block, LDS cursors) ----------------
__global__ __launch_bounds__(256) void scanbuild_kernel(
    const int* __restrict__ counts, int* __restrict__ offsets,
    const int* __restrict__ topk_idx, const float* __restrict__ topk_w,
    int* __restrict__ token_list, float* __restrict__ slot_w,
    int* __restrict__ slot_of) {
    __shared__ int cur_s[NEXP];
    if (threadIdx.x == 0) {
        int o = 0;
        for (int e = 0; e < NEXP; ++e) { offsets[e] = o; cur_s[e] = o; o += counts[e]; }
        offsets[NEXP] = o;
    }
    __syncthreads();
    for (int t = threadIdx.x; t < TOKENS; t += 256) {
#pragma unroll
        for (int k = 0; k < 4; ++k) {
            int e = topk_idx[t * 4 + k];
            int pos = atomicAdd(&cur_s[e], 1);
            token_list[pos] = t;
            slot_w[pos] = topk_w[t * 4 + k];
            slot_of[t * 4 + k] = pos;
        }
    }
}

// ------- fused weight transpose+convert: both [E][K][N] f32 -> [E][N][K] bf16 ----
// y in [0,16): gup tile (n0 = x*64, k0 = y*64), K=1024, N=4096
// y in [16,24): down tile via idx = (y-16)*64 + x, K=2048, N=1024
__global__ __launch_bounds__(256) void transpose_cvt2_kernel(
    const float* __restrict__ gup, ushort* __restrict__ gupT,
    const float* __restrict__ dwp, ushort* __restrict__ downT) {
    const int e = blockIdx.z;
    const float* src; ushort* dst;
    int K, N, n0, k0;
    if (blockIdx.y < 16) {
        src = gup; dst = gupT; K = HD; N = TWO_I;
        n0 = blockIdx.x * 64; k0 = blockIdx.y * 64;
    } else {
        src = dwp; dst = downT; K = ID; N = HD;
        const int idx = (blockIdx.y - 16) * 64 + blockIdx.x;   // [0,512)
        n0 = (idx & 15) * 64; k0 = (idx >> 4) * 64;
    }
    __shared__ float T[64][68];
    const float* s = src + (size_t)e * K * N + (size_t)k0 * N + n0;
    const int r = threadIdx.x >> 4;
    const int c4 = (threadIdx.x & 15) * 4;
#pragma unroll
    for (int i = 0; i < 64; i += 16) {
        float4 v = *(const float4*)(s + (size_t)(r + i) * N + c4);
        T[r + i][c4 + 0] = v.x; T[r + i][c4 + 1] = v.y;
        T[r + i][c4 + 2] = v.z; T[r + i][c4 + 3] = v.w;
    }
    __syncthreads();
    const int n = threadIdx.x >> 2;
    const int kc = (threadIdx.x & 3) * 16;
    union { ushort b[16]; short8 v[2]; } o;
#pragma unroll
    for (int j = 0; j < 16; ++j) o.b[j] = f2bf(T[kc + j][n]);
    ushort* d = dst + (size_t)e * N * K + (size_t)(n0 + n) * K + k0 + kc;
    *(short8*)(d) = o.v[0];
    *(short8*)(d + 8) = o.v[1];
}

// ====== grouped 128x128 GEMMs: triple-buffered LDS, depth-2 counted-vmcnt ======
// 3 tiles in flight; steady-state wait vmcnt(8) covers a load issued TWO phases
// earlier (~2x the latency slack of double-buffering). LDS 48 KB/block.

// ---- GEMM1: act[slot][I] = GLU((hb[tok] . gupT[e]) + bias) ----
__global__ __launch_bounds__(256) void gemm1_t_kernel(
    const ushort* __restrict__ hb, const ushort* __restrict__ gupT,
    const float* __restrict__ gub, const int* __restrict__ offsets,
    const int* __restrict__ token_list, ushort* __restrict__ act) {
    const int e = blockIdx.z;
    const int so = offsets[e];
    const int ne = offsets[e + 1] - so;
    const int row0 = blockIdx.y * 128;
    if (row0 >= ne) return;
    const int n0 = blockIdx.x * 128;

    __shared__ ushort As[3][4096];
    __shared__ ushort Bs[3][4096];

    const int tid = threadIdx.x;
    const int lane = tid & 63;
    const int w = tid >> 6;
    const int m = lane & 15;
    const int q = lane >> 4;
    const int wm = (w >> 1) * 64;
    const int wn = (w & 1) * 64;

    const int r0 = tid >> 2;
    const int ce = (tid & 3) * 8;
    int ar0 = row0 + r0;       if (ar0 >= ne) ar0 = ne - 1;
    int ar1 = row0 + 64 + r0;  if (ar1 >= ne) ar1 = ne - 1;
    const ushort* ga0 = hb + (size_t)token_list[so + ar0] * HD + ce;
    const ushort* ga1 = hb + (size_t)token_list[so + ar1] * HD + ce;
    const ushort* gb0 = gupT + (size_t)e * TWO_I * HD + (size_t)(n0 + r0) * HD + ce;
    const ushort* gb1 = gb0 + (size_t)64 * HD;

    f32x4 acc[4][4] = {};

#define STAGE1(B, K0) do { \
    gload_lds16(ga0 + (K0), As[B] + w * 512); \
    gload_lds16(ga1 + (K0), As[B] + 2048 + w * 512); \
    gload_lds16(gb0 + (K0), Bs[B] + w * 512); \
    gload_lds16(gb1 + (K0), Bs[B] + 2048 + w * 512); \
} while (0)

#define COMPUTE1(B) do { \
    short8 af[4], bfr[4]; \
    _Pragma("unroll") for (int rt = 0; rt < 4; ++rt) \
        af[rt] = *(const short8*)(As[B] + (wm + rt * 16 + m) * 32 + q * 8); \
    _Pragma("unroll") for (int c = 0; c < 4; ++c) \
        bfr[c] = *(const short8*)(Bs[B] + (wn + c * 16 + m) * 32 + q * 8); \
    _Pragma("unroll") for (int rt = 0; rt < 4; ++rt) \
        _Pragma("unroll") for (int c = 0; c < 4; ++c) \
            acc[rt][c] = __builtin_amdgcn_mfma_f32_16x16x32_bf16(af[rt], bfr[c], acc[rt][c], 0, 0, 0); \
} while (0)

    STAGE1(0, 0);
    STAGE1(1, 32);
    int cur = 0;
    for (int t = 0; t < HD / 32 - 2; ++t) {
        int nxt = cur + 2; if (nxt >= 3) nxt -= 3;
        STAGE1(nxt, (t + 2) * 32);                         // 12 loads in flight
        asm volatile("s_waitcnt vmcnt(8)" ::: "memory");   // tile t landed (this wave)
        __builtin_amdgcn_s_barrier();                      // all waves' tile t landed
        __builtin_amdgcn_s_setprio(1);
        COMPUTE1(cur);
        __builtin_amdgcn_s_setprio(0);
        __builtin_amdgcn_s_barrier();                      // buf cur free for reuse
        cur = (cur == 2) ? 0 : cur + 1;
    }
    asm volatile("s_waitcnt vmcnt(4)" ::: "memory");       // tile NT-2 landed
    __builtin_amdgcn_s_barrier();
    COMPUTE1(cur);
    cur = (cur == 2) ? 0 : cur + 1;
    asm volatile("s_waitcnt vmcnt(0)" ::: "memory");       // tile NT-1 landed
    __builtin_amdgcn_s_barrier();
    COMPUTE1(cur);

#pragma unroll
    for (int c = 0; c < 4; ++c) {
        const int n = n0 + wn + c * 16 + m;
        const float bias = gub[e * TWO_I + n];
#pragma unroll
        for (int rt = 0; rt < 4; ++rt) {
#pragma unroll
            for (int rr = 0; rr < 4; ++rr) {
                const int grow = row0 + wm + rt * 16 + q * 4 + rr;
                float v = acc[rt][c][rr] + bias;
                float pv = __shfl_xor(v, 1);
                float gate = (m & 1) ? pv : v;
                float up   = (m & 1) ? v : pv;
                gate = fminf(gate, 7.0f);
                up = fminf(fmaxf(up, -7.0f), 7.0f);
                float glu = gate / (1.0f + __expf(-1.702f * gate));
                float a = (up + 1.0f) * glu;
                if (!(m & 1) && grow < ne)
                    act[(size_t)(so + grow) * ID + (n >> 1)] = f2bf(a);
            }
        }
    }
}

// ---- GEMM2: dslot[slot][H] = act[slot] . downT[e]  (raw fp32, no bias/weight) ----
__global__ __launch_bounds__(256) void gemm2_t_kernel(
    const ushort* __restrict__ act, const ushort* __restrict__ downT,
    const int* __restrict__ offsets, float* __restrict__ dslot) {
    const int e = blockIdx.z;
    const int so = offsets[e];
    const int ne = offsets[e + 1] - so;
    const int row0 = blockIdx.y * 128;
    if (row0 >= ne) return;
    const int n0 = blockIdx.x * 128;

    __shared__ ushort As[3][4096];
    __shared__ ushort Bs[3][4096];

    const int tid = threadIdx.x;
    const int lane = tid & 63;
    const int w = tid >> 6;
    const int m = lane & 15;
    const int q = lane >> 4;
    const int wm = (w >> 1) * 64;
    const int wn = (w & 1) * 64;

    const int r0 = tid >> 2;
    const int ce = (tid & 3) * 8;
    // A rows (slots) are contiguous per expert; act has 128 rows of slack.
    const ushort* ga0 = act + (size_t)(so + row0 + r0) * ID + ce;
    const ushort* ga1 = ga0 + (size_t)64 * ID;
    const ushort* gb0 = downT + (size_t)e * HD * ID + (size_t)(n0 + r0) * ID + ce;
    const ushort* gb1 = gb0 + (size_t)64 * ID;

    f32x4 acc[4][4] = {};

#define STAGE2(B, K0) do { \
    gload_lds16(ga0 + (K0), As[B] + w * 512); \
    gload_lds16(ga1 + (K0), As[B] + 2048 + w * 512); \
    gload_lds16(gb0 + (K0), Bs[B] + w * 512); \
    gload_lds16(gb1 + (K0), Bs[B] + 2048 + w * 512); \
} while (0)

#define COMPUTE2(B) do { \
    short8 af[4], bfr[4]; \
    _Pragma("unroll") for (int rt = 0; rt < 4; ++rt) \
        af[rt] = *(const short8*)(As[B] + (wm + rt * 16 + m) * 32 + q * 8); \
    _Pragma("unroll") for (int c = 0; c < 4; ++c) \
        bfr[c] = *(const short8*)(Bs[B] + (wn + c * 16 + m) * 32 + q * 8); \
    _Pragma("unroll") for (int rt = 0; rt < 4; ++rt) \
        _Pragma("unroll") for (int c = 0; c < 4; ++c) \
            acc[rt][c] = __builtin_amdgcn_mfma_f32_16x16x32_bf16(af[rt], bfr[c], acc[rt][c], 0, 0, 0); \
} while (0)

    STAGE2(0, 0);
    STAGE2(1, 32);
    int cur = 0;
    for (int t = 0; t < ID / 32 - 2; ++t) {
        int nxt = cur + 2; if (nxt >= 3) nxt -= 3;
        STAGE2(nxt, (t + 2) * 32);
        asm volatile("s_waitcnt vmcnt(8)" ::: "memory");
        __builtin_amdgcn_s_barrier();
        __builtin_amdgcn_s_setprio(1);
        COMPUTE2(cur);
        __builtin_amdgcn_s_setprio(0);
        __builtin_amdgcn_s_barrier();
        cur = (cur == 2) ? 0 : cur + 1;
    }
    asm volatile("s_waitcnt vmcnt(4)" ::: "memory");
    __builtin_amdgcn_s_barrier();
    COMPUTE2(cur);
    cur = (cur == 2) ? 0 : cur + 1;
    asm volatile("s_waitcnt vmcnt(0)" ::: "memory");
    __builtin_amdgcn_s_barrier();
    COMPUTE2(cur);

    // plain coalesced fp32 stores — no atomics, no bias/weight (combine does it)
#pragma unroll
    for (int rt = 0; rt < 4; ++rt) {
#pragma unroll
        for (int rr = 0; rr < 4; ++rr) {
            const int grow = row0 + wm + rt * 16 + q * 4 + rr;
            if (grow < ne) {
                float* dp = dslot + (size_t)(so + grow) * HD + n0 + wn + m;
#pragma unroll
                for (int c = 0; c < 4; ++c) dp[c * 16] = acc[rt][c][rr];
            }
        }
    }
}

// ---- combine: out[t] = sum_k w_k * (dslot[slot_k] + bias[e_k]) ----
__global__ __launch_bounds__(256) void combine_kernel(
    const float* __restrict__ dslot, const float* __restrict__ dwb,
    const int* __restrict__ topk_idx, const int* __restrict__ slot_of,
    const float* __restrict__ topk_w, float* __restrict__ out) {
    const int t = blockIdx.x;
    const int n = threadIdx.x * 4;
    float4 o = {0.f, 0.f, 0.f, 0.f};
#pragma unroll
    for (int k = 0; k < 4; ++k) {
        const int e = topk_idx[t * 4 + k];
        const int s = slot_of[t * 4 + k];
        const float wgt = topk_w[t * 4 + k];
        float4 d = *(const float4*)(dslot + (size_t)s * HD + n);
        float4 b = *(const float4*)(dwb + (size_t)e * HD + n);
        o.x += wgt * (d.x + b.x);
        o.y += wgt * (d.y + b.y);
        o.z += wgt * (d.z + b.z);
        o.w += wgt * (d.w + b.w);
    }
    *(float4*)(out + (size_t)t * HD + n) = o;
}

// ============ FALLBACK PATH (used only if ws too small) ============

__global__ __launch_bounds__(256) void gemm1_fb_kernel(
    const ushort* __restrict__ hb, const float* __restrict__ gup,
    const float* __restrict__ gub, const int* __restrict__ offsets,
    const int* __restrict__ token_list, ushort* __restrict__ act) {
    const int e = blockIdx.z;
    const int so = offsets[e];
    const int ne = offsets[e + 1] - so;
    const int row0 = blockIdx.y * 64;
    if (row0 >= ne) return;
    const int n0 = blockIdx.x * 64;
    __shared__ ushort Al[64][40];
    __shared__ ushort Bt[64][40];
    const int tid = threadIdx.x;
    const int lane = tid & 63;
    const int wave = tid >> 6;
    const int m = lane & 15;
    const int q = lane >> 4;
    const int ar = tid >> 2;
    const int ac = (tid & 3) * 8;
    int arow = row0 + ar; if (arow >= ne) arow = ne - 1;
    const int tok = token_list[so + arow];
    const ushort* aptr = hb + tok * HD + ac;
    const int bk = tid >> 3;
    const int bn = (tid & 7) * 8;
    const float* bptr = gup + (size_t)e * HD * TWO_I + (size_t)bk * TWO_I + n0 + bn;
    f32x4 acc[4] = {{0,0,0,0},{0,0,0,0},{0,0,0,0},{0,0,0,0}};
    for (int k0 = 0; k0 < HD; k0 += 32) {
        float4 av = *(const float4*)(aptr + k0);
        *(float4*)(&Al[ar][ac]) = av;
        const float* bp = bptr + (size_t)k0 * TWO_I;
        float4 b0 = *(const float4*)(bp);
        float4 b1 = *(const float4*)(bp + 4);
        Bt[bn + 0][bk] = f2bf(b0.x); Bt[bn + 1][bk] = f2bf(b0.y);
        Bt[bn + 2][bk] = f2bf(b0.z); Bt[bn + 3][bk] = f2bf(b0.w);
        Bt[bn + 4][bk] = f2bf(b1.x); Bt[bn + 5][bk] = f2bf(b1.y);
        Bt[bn + 6][bk] = f2bf(b1.z); Bt[bn + 7][bk] = f2bf(b1.w);
        __syncthreads();
        short8 af = *(const short8*)(&Al[wave * 16 + m][q * 8]);
#pragma unroll
        for (int c = 0; c < 4; ++c) {
            short8 bf = *(const short8*)(&Bt[c * 16 + m][q * 8]);
            acc[c] = __builtin_amdgcn_mfma_f32_16x16x32_bf16(af, bf, acc[c], 0, 0, 0);
        }
        __syncthreads();
    }
#pragma unroll
    for (int c = 0; c < 4; ++c) {
        const int n = n0 + c * 16 + m;
        const float bias = gub[e * TWO_I + n];
#pragma unroll
        for (int r = 0; r < 4; ++r) {
            const int grow = row0 + wave * 16 + q * 4 + r;
            float v = acc[c][r] + bias;
            float pv = __shfl_xor(v, 1);
            float gate = (m & 1) ? pv : v;
            float up   = (m & 1) ? v : pv;
            gate = fminf(gate, 7.0f);
            up = fminf(fmaxf(up, -7.0f), 7.0f);
            float glu = gate / (1.0f + __expf(-1.702f * gate));
            float a = (up + 1.0f) * glu;
            if (!(m & 1) && grow < ne)
                act[(size_t)(so + grow) * ID + (n >> 1)] = f2bf(a);
        }
    }
}

__global__ __launch_bounds__(256) void gemm2_fb_kernel(
    const ushort* __restrict__ act, const float* __restrict__ dwp,
    const float* __restrict__ dwb, const int* __restrict__ offsets,
    const int* __restrict__ token_list, const float* __restrict__ slot_w,
    float* __restrict__ out) {
    const int e = blockIdx.z;
    const int so = offsets[e];
    const int ne = offsets[e + 1] - so;
    const int row0 = blockIdx.y * 64;
    if (row0 >= ne) return;
    const int n0 = blockIdx.x * 64;
    __shared__ ushort Al[64][40];
    __shared__ ushort Bt[64][40];
    const int tid = threadIdx.x;
    const int lane = tid & 63;
    const int wave = tid >> 6;
    const int m = lane & 15;
    const int q = lane >> 4;
    const int ar = tid >> 2;
    const int ac = (tid & 3) * 8;
    int arow = row0 + ar; if (arow >= ne) arow = ne - 1;
    const ushort* aptr = act + (size_t)(so + arow) * ID + ac;
    const int bk = tid >> 3;
    const int bn = (tid & 7) * 8;
    const float* bptr = dwp + (size_t)e * ID * HD + (size_t)bk * HD + n0 + bn;
    f32x4 acc[4] = {{0,0,0,0},{0,0,0,0},{0,0,0,0},{0,0,0,0}};
    for (int k0 = 0; k0 < ID; k0 += 32) {
        float4 av = *(const float4*)(aptr + k0);
        *(float4*)(&Al[ar][ac]) = av;
        const float* bp = bptr + (size_t)k0 * HD;
        float4 b0 = *(const float4*)(bp);
        float4 b1 = *(const float4*)(bp + 4);
        Bt[bn + 0][bk] = f2bf(b0.x); Bt[bn + 1][bk] = f2bf(b0.y);
        Bt[bn + 2][bk] = f2bf(b0.z); Bt[bn + 3][bk] = f2bf(b0.w);
        Bt[bn + 4][bk] = f2bf(b1.x); Bt[bn + 5][bk] = f2bf(b1.y);
        Bt[bn + 6][bk] = f2bf(b1.z); Bt[bn + 7][bk] = f2bf(b1.w);
        __syncthreads();
        short8 af = *(const short8*)(&Al[wave * 16 + m][q * 8]);
#pragma unroll
        for (int c = 0; c < 4; ++c) {
            short8 bf = *(const short8*)(&Bt[c * 16 + m][q * 8]);
            acc[c] = __builtin_amdgcn_mfma_f32_16x16x32_bf16(af, bf, acc[c], 0, 0, 0);
        }
        __syncthreads();
    }
#pragma unroll
    for (int r = 0; r < 4; ++r) {
        const int grow = row0 + wave * 16 + q * 4 + r;
        if (grow < ne) {
            const int slot = so + grow;
            const int tok = token_list[slot];
            const float wgt = slot_w[slot];
#pragma unroll
            for (int c = 0; c < 4; ++c) {
                const int n = n0 + c * 16 + m;
                atomicAdd(&out[tok * HD + n], (acc[c][r] + dwb[e * HD + n]) * wgt);
            }
        }
    }
}

extern "C" void kernel_launch(void* const* d_in, const int* in_sizes, int n_in,
                              void* d_out, int out_size, void* d_ws, size_t ws_size,
                              hipStream_t stream) {
    const float* hs  = (const float*)d_in[0];
    const float* rw  = (const float*)d_in[1];
    const float* rb  = (const float*)d_in[2];
    const float* gup = (const float*)d_in[3];
    const float* gub = (const float*)d_in[4];
    const float* dwp = (const float*)d_in[5];
    const float* dwb = (const float*)d_in[6];

    float* out = (float*)d_out;                       // [2048,1024] fp32
    float* topk_w = out + (size_t)TOKENS * HD;        // [2048,4] fp32

    char* w = (char*)d_ws;
    int* counts     = (int*)(w + 0);
    int* offsets    = (int*)(w + 128);
    int* token_list = (int*)(w + 256);
    float* slot_w   = (float*)(w + 256 + 32768);
    int* topk_idx   = (int*)(w + 256 + 65536);
    int* slot_of    = (int*)(w + 256 + 98304);
    ushort* hb      = (ushort*)(w + ((size_t)1 << 20));           // 4 MB
    ushort* act     = (ushort*)(w + ((size_t)6 << 20));           // 8320x2048 bf16 (~34MB)
    ushort* gupT    = (ushort*)(w + ((size_t)41 << 20));          // 128 MB
    ushort* downT   = (ushort*)(w + ((size_t)169 << 20));         // 64 MB
    float* dslot    = (float*)(w + ((size_t)233 << 20));          // 8192x1024 fp32 (32 MB)
    const size_t need = (size_t)266 << 20;

    hipMemsetAsync(w, 0, 128, stream);

    router_kernel<<<512, 256, 0, stream>>>(hs, rw, rb, topk_w, topk_idx, counts, hb);
    scanbuild_kernel<<<1, 256, 0, stream>>>(counts, offsets, topk_idx, topk_w,
                                            token_list, slot_w, slot_of);

    if (ws_size >= need) {
        transpose_cvt2_kernel<<<dim3(64, 24, NEXP), 256, 0, stream>>>(
            gup, gupT, dwp, downT);
        gemm1_t_kernel<<<dim3(TWO_I / 128, TOKENS / 128, NEXP), 256, 0, stream>>>(
            hb, gupT, gub, offsets, token_list, act);
        gemm2_t_kernel<<<dim3(HD / 128, TOKENS / 128, NEXP), 256, 0, stream>>>(
            act, downT, offsets, dslot);
        combine_kernel<<<TOKENS, 256, 0, stream>>>(dslot, dwb, topk_idx, slot_of, topk_w, out);
    } else {
        // fallback: fp32 weights converted in-tile; atomic accumulate into zeroed out
        hipMemsetAsync(out, 0, (size_t)TOKENS * HD * sizeof(float), stream);
        gemm1_fb_kernel<<<dim3(TWO_I / 64, TOKENS / 64, NEXP), 256, 0, stream>>>(
            hb, gup, gub, offsets, token_list, act);
        gemm2_fb_kernel<<<dim3(HD / 64, TOKENS / 64, NEXP), 256, 0, stream>>>(
            act, dwp, dwb, offsets, token_list, slot_w, out);
    }
}

// Round 5
// 801.802 us; speedup vs baseline: 1.0578x; 1.0043x over previous
//
#include <hip/hip_runtime.h>

#define TOKENS 2048
#define HD 1024
#define NEXP 16
#define TWO_I 4096
#define ID 2048

typedef short short8 __attribute__((ext_vector_type(8)));
typedef float f32x4 __attribute__((ext_vector_type(4)));
typedef unsigned short ushort;

static __device__ __forceinline__ ushort f2bf(float f) {
    union { float f; unsigned u; } v; v.f = f;
    unsigned r = v.u + 0x7FFFu + ((v.u >> 16) & 1u);
    return (ushort)(r >> 16);
}

static __device__ __forceinline__ void gload_lds16(const void* g, void* l) {
    __builtin_amdgcn_global_load_lds(
        (const __attribute__((address_space(1))) unsigned int*)(g),
        (__attribute__((address_space(3))) unsigned int*)(l), 16, 0, 0);
}

// ---------------- router (+ fused hidden fp32->bf16 convert) ----------------
__global__ __launch_bounds__(256) void router_kernel(
    const float* __restrict__ hs, const float* __restrict__ rw,
    const float* __restrict__ rb, float* __restrict__ topk_w_out,
    int* __restrict__ topk_idx, int* __restrict__ counts,
    ushort* __restrict__ hb) {
    // fused convert: this block's 4 tokens = 4096 floats, 16 per thread
    {
        const int i = blockIdx.x * 4096 + threadIdx.x * 16;
#pragma unroll
        for (int j = 0; j < 4; ++j) {
            float4 v = *(const float4*)(hs + i + j * 4);
            union { ushort b[4]; float2 f2; } u;
            u.b[0] = f2bf(v.x); u.b[1] = f2bf(v.y);
            u.b[2] = f2bf(v.z); u.b[3] = f2bf(v.w);
            *(float2*)(hb + i + j * 4) = u.f2;
        }
    }

    const int wave = threadIdx.x >> 6;
    const int lane = threadIdx.x & 63;
    const int t = blockIdx.x * 4 + wave;

    float h[16];
#pragma unroll
    for (int j = 0; j < 16; ++j) h[j] = hs[t * HD + j * 64 + lane];

    __shared__ float lg[4][NEXP];
#pragma unroll
    for (int e = 0; e < NEXP; ++e) {
        float acc = 0.f;
#pragma unroll
        for (int j = 0; j < 16; ++j) acc += h[j] * rw[e * HD + j * 64 + lane];
#pragma unroll
        for (int s = 32; s > 0; s >>= 1) acc += __shfl_xor(acc, s);
        if (lane == 0) lg[wave][e] = acc + rb[e];
    }
    if (lane == 0) {
        float mx = lg[wave][0];
        for (int e = 1; e < NEXP; ++e) mx = fmaxf(mx, lg[wave][e]);
        float pr[NEXP];
        for (int e = 0; e < NEXP; ++e) pr[e] = __expf(lg[wave][e] - mx);
        int idx[4]; float wv[4]; float sum4 = 0.f;
        for (int k = 0; k < 4; ++k) {
            int bi = 0; float bv = -1.f;
            for (int e = 0; e < NEXP; ++e)
                if (pr[e] > bv) { bv = pr[e]; bi = e; }
            idx[k] = bi; wv[k] = bv; pr[bi] = -2.f; sum4 += bv;
        }
        for (int k = 0; k < 4; ++k) {
            topk_w_out[t * 4 + k] = wv[k] / sum4;
            topk_idx[t * 4 + k] = idx[k];
            atomicAdd(&counts[idx[k]], 1);
        }
    }
}

// ---------------- fused scan + build (single block, LDS cursors) ----------------
__global__ __launch_bounds__(256) void scanbuild_kernel(
    const int* __restrict__ counts, int* __restrict__ offsets,
    const int* __restrict__ topk_idx, const float* __restrict__ topk_w,
    int* __restrict__ token_list, float* __restrict__ slot_w,
    int* __restrict__ slot_of) {
    __shared__ int cur_s[NEXP];
    if (threadIdx.x == 0) {
        int o = 0;
        for (int e = 0; e < NEXP; ++e) { offsets[e] = o; cur_s[e] = o; o += counts[e]; }
        offsets[NEXP] = o;
    }
    __syncthreads();
    for (int t = threadIdx.x; t < TOKENS; t += 256) {
#pragma unroll
        for (int k = 0; k < 4; ++k) {
            int e = topk_idx[t * 4 + k];
            int pos = atomicAdd(&cur_s[e], 1);
            token_list[pos] = t;
            slot_w[pos] = topk_w[t * 4 + k];
            slot_of[t * 4 + k] = pos;
        }
    }
}

// ------- fused weight transpose+convert: both [E][K][N] f32 -> [E][N][K] bf16 ----
// LDS tile padded to 65 (stride mod 32 == 1): write banks (r+c4+k)%32 and read
// banks (kc+j+n)%32 are both exactly 2-way across a 64-lane wave (2-way is free).
// The old pad of 68 (stride mod 32 == 4) collapsed 4*kc%32 to 0 -> 4-way conflict
// on every read (9.4M conflict cycles/dispatch).
__global__ __launch_bounds__(256) void transpose_cvt2_kernel(
    const float* __restrict__ gup, ushort* __restrict__ gupT,
    const float* __restrict__ dwp, ushort* __restrict__ downT) {
    const int e = blockIdx.z;
    const float* src; ushort* dst;
    int K, N, n0, k0;
    if (blockIdx.y < 16) {
        src = gup; dst = gupT; K = HD; N = TWO_I;
        n0 = blockIdx.x * 64; k0 = blockIdx.y * 64;
    } else {
        src = dwp; dst = downT; K = ID; N = HD;
        const int idx = (blockIdx.y - 16) * 64 + blockIdx.x;   // [0,512)
        n0 = (idx & 15) * 64; k0 = (idx >> 4) * 64;
    }
    __shared__ float T[64][65];
    const float* s = src + (size_t)e * K * N + (size_t)k0 * N + n0;
    const int r = threadIdx.x >> 4;
    const int c4 = (threadIdx.x & 15) * 4;
#pragma unroll
    for (int i = 0; i < 64; i += 16) {
        float4 v = *(const float4*)(s + (size_t)(r + i) * N + c4);
        T[r + i][c4 + 0] = v.x; T[r + i][c4 + 1] = v.y;
        T[r + i][c4 + 2] = v.z; T[r + i][c4 + 3] = v.w;
    }
    __syncthreads();
    const int n = threadIdx.x >> 2;
    const int kc = (threadIdx.x & 3) * 16;
    union { ushort b[16]; short8 v[2]; } o;
#pragma unroll
    for (int j = 0; j < 16; ++j) o.b[j] = f2bf(T[kc + j][n]);
    ushort* d = dst + (size_t)e * N * K + (size_t)(n0 + n) * K + k0 + kc;
    *(short8*)(d) = o.v[0];
    *(short8*)(d + 8) = o.v[1];
}

// ====== grouped 128x128 GEMMs: triple-buffered LDS, depth-2 counted-vmcnt ======
// 3 tiles in flight; steady-state wait vmcnt(8) covers a load issued TWO phases
// earlier (~2x the latency slack of double-buffering). LDS 48 KB/block.

// ---- GEMM1: act[slot][I] = GLU((hb[tok] . gupT[e]) + bias) ----
__global__ __launch_bounds__(256) void gemm1_t_kernel(
    const ushort* __restrict__ hb, const ushort* __restrict__ gupT,
    const float* __restrict__ gub, const int* __restrict__ offsets,
    const int* __restrict__ token_list, ushort* __restrict__ act) {
    const int e = blockIdx.z;
    const int so = offsets[e];
    const int ne = offsets[e + 1] - so;
    const int row0 = blockIdx.y * 128;
    if (row0 >= ne) return;
    const int n0 = blockIdx.x * 128;

    __shared__ ushort As[3][4096];
    __shared__ ushort Bs[3][4096];

    const int tid = threadIdx.x;
    const int lane = tid & 63;
    const int w = tid >> 6;
    const int m = lane & 15;
    const int q = lane >> 4;
    const int wm = (w >> 1) * 64;
    const int wn = (w & 1) * 64;

    const int r0 = tid >> 2;
    const int ce = (tid & 3) * 8;
    int ar0 = row0 + r0;       if (ar0 >= ne) ar0 = ne - 1;
    int ar1 = row0 + 64 + r0;  if (ar1 >= ne) ar1 = ne - 1;
    const ushort* ga0 = hb + (size_t)token_list[so + ar0] * HD + ce;
    const ushort* ga1 = hb + (size_t)token_list[so + ar1] * HD + ce;
    const ushort* gb0 = gupT + (size_t)e * TWO_I * HD + (size_t)(n0 + r0) * HD + ce;
    const ushort* gb1 = gb0 + (size_t)64 * HD;

    f32x4 acc[4][4] = {};

#define STAGE1(B, K0) do { \
    gload_lds16(ga0 + (K0), As[B] + w * 512); \
    gload_lds16(ga1 + (K0), As[B] + 2048 + w * 512); \
    gload_lds16(gb0 + (K0), Bs[B] + w * 512); \
    gload_lds16(gb1 + (K0), Bs[B] + 2048 + w * 512); \
} while (0)

#define COMPUTE1(B) do { \
    short8 af[4], bfr[4]; \
    _Pragma("unroll") for (int rt = 0; rt < 4; ++rt) \
        af[rt] = *(const short8*)(As[B] + (wm + rt * 16 + m) * 32 + q * 8); \
    _Pragma("unroll") for (int c = 0; c < 4; ++c) \
        bfr[c] = *(const short8*)(Bs[B] + (wn + c * 16 + m) * 32 + q * 8); \
    _Pragma("unroll") for (int rt = 0; rt < 4; ++rt) \
        _Pragma("unroll") for (int c = 0; c < 4; ++c) \
            acc[rt][c] = __builtin_amdgcn_mfma_f32_16x16x32_bf16(af[rt], bfr[c], acc[rt][c], 0, 0, 0); \
} while (0)

    STAGE1(0, 0);
    STAGE1(1, 32);
    int cur = 0;
    for (int t = 0; t < HD / 32 - 2; ++t) {
        int nxt = cur + 2; if (nxt >= 3) nxt -= 3;
        STAGE1(nxt, (t + 2) * 32);                         // 12 loads in flight
        asm volatile("s_waitcnt vmcnt(8)" ::: "memory");   // tile t landed (this wave)
        __builtin_amdgcn_s_barrier();                      // all waves' tile t landed
        __builtin_amdgcn_s_setprio(1);
        COMPUTE1(cur);
        __builtin_amdgcn_s_setprio(0);
        __builtin_amdgcn_s_barrier();                      // buf cur free for reuse
        cur = (cur == 2) ? 0 : cur + 1;
    }
    asm volatile("s_waitcnt vmcnt(4)" ::: "memory");       // tile NT-2 landed
    __builtin_amdgcn_s_barrier();
    COMPUTE1(cur);
    cur = (cur == 2) ? 0 : cur + 1;
    asm volatile("s_waitcnt vmcnt(0)" ::: "memory");       // tile NT-1 landed
    __builtin_amdgcn_s_barrier();
    COMPUTE1(cur);

#pragma unroll
    for (int c = 0; c < 4; ++c) {
        const int n = n0 + wn + c * 16 + m;
        const float bias = gub[e * TWO_I + n];
#pragma unroll
        for (int rt = 0; rt < 4; ++rt) {
#pragma unroll
            for (int rr = 0; rr < 4; ++rr) {
                const int grow = row0 + wm + rt * 16 + q * 4 + rr;
                float v = acc[rt][c][rr] + bias;
                float pv = __shfl_xor(v, 1);
                float gate = (m & 1) ? pv : v;
                float up   = (m & 1) ? v : pv;
                gate = fminf(gate, 7.0f);
                up = fminf(fmaxf(up, -7.0f), 7.0f);
                float glu = gate / (1.0f + __expf(-1.702f * gate));
                float a = (up + 1.0f) * glu;
                if (!(m & 1) && grow < ne)
                    act[(size_t)(so + grow) * ID + (n >> 1)] = f2bf(a);
            }
        }
    }
}

// ---- GEMM2: dslot[slot][H] = act[slot] . downT[e]  (raw fp32, no bias/weight) ----
__global__ __launch_bounds__(256) void gemm2_t_kernel(
    const ushort* __restrict__ act, const ushort* __restrict__ downT,
    const int* __restrict__ offsets, float* __restrict__ dslot) {
    const int e = blockIdx.z;
    const int so = offsets[e];
    const int ne = offsets[e + 1] - so;
    const int row0 = blockIdx.y * 128;
    if (row0 >= ne) return;
    const int n0 = blockIdx.x * 128;

    __shared__ ushort As[3][4096];
    __shared__ ushort Bs[3][4096];

    const int tid = threadIdx.x;
    const int lane = tid & 63;
    const int w = tid >> 6;
    const int m = lane & 15;
    const int q = lane >> 4;
    const int wm = (w >> 1) * 64;
    const int wn = (w & 1) * 64;

    const int r0 = tid >> 2;
    const int ce = (tid & 3) * 8;
    // A rows (slots) are contiguous per expert; act has 128 rows of slack.
    const ushort* ga0 = act + (size_t)(so + row0 + r0) * ID + ce;
    const ushort* ga1 = ga0 + (size_t)64 * ID;
    const ushort* gb0 = downT + (size_t)e * HD * ID + (size_t)(n0 + r0) * ID + ce;
    const ushort* gb1 = gb0 + (size_t)64 * ID;

    f32x4 acc[4][4] = {};

#define STAGE2(B, K0) do { \
    gload_lds16(ga0 + (K0), As[B] + w * 512); \
    gload_lds16(ga1 + (K0), As[B] + 2048 + w * 512); \
    gload_lds16(gb0 + (K0), Bs[B] + w * 512); \
    gload_lds16(gb1 + (K0), Bs[B] + 2048 + w * 512); \
} while (0)

#define COMPUTE2(B) do { \
    short8 af[4], bfr[4]; \
    _Pragma("unroll") for (int rt = 0; rt < 4; ++rt) \
        af[rt] = *(const short8*)(As[B] + (wm + rt * 16 + m) * 32 + q * 8); \
    _Pragma("unroll") for (int c = 0; c < 4; ++c) \
        bfr[c] = *(const short8*)(Bs[B] + (wn + c * 16 + m) * 32 + q * 8); \
    _Pragma("unroll") for (int rt = 0; rt < 4; ++rt) \
        _Pragma("unroll") for (int c = 0; c < 4; ++c) \
            acc[rt][c] = __builtin_amdgcn_mfma_f32_16x16x32_bf16(af[rt], bfr[c], acc[rt][c], 0, 0, 0); \
} while (0)

    STAGE2(0, 0);
    STAGE2(1, 32);
    int cur = 0;
    for (int t = 0; t < ID / 32 - 2; ++t) {
        int nxt = cur + 2; if (nxt >= 3) nxt -= 3;
        STAGE2(nxt, (t + 2) * 32);
        asm volatile("s_waitcnt vmcnt(8)" ::: "memory");
        __builtin_amdgcn_s_barrier();
        __builtin_amdgcn_s_setprio(1);
        COMPUTE2(cur);
        __builtin_amdgcn_s_setprio(0);
        __builtin_amdgcn_s_barrier();
        cur = (cur == 2) ? 0 : cur + 1;
    }
    asm volatile("s_waitcnt vmcnt(4)" ::: "memory");
    __builtin_amdgcn_s_barrier();
    COMPUTE2(cur);
    cur = (cur == 2) ? 0 : cur + 1;
    asm volatile("s_waitcnt vmcnt(0)" ::: "memory");
    __builtin_amdgcn_s_barrier();
    COMPUTE2(cur);

    // plain coalesced fp32 stores — no atomics, no bias/weight (combine does it)
#pragma unroll
    for (int rt = 0; rt < 4; ++rt) {
#pragma unroll
        for (int rr = 0; rr < 4; ++rr) {
            const int grow = row0 + wm + rt * 16 + q * 4 + rr;
            if (grow < ne) {
                float* dp = dslot + (size_t)(so + grow) * HD + n0 + wn + m;
#pragma unroll
                for (int c = 0; c < 4; ++c) dp[c * 16] = acc[rt][c][rr];
            }
        }
    }
}

// ---- combine: out[t] = sum_k w_k * (dslot[slot_k] + bias[e_k]) ----
__global__ __launch_bounds__(256) void combine_kernel(
    const float* __restrict__ dslot, const float* __restrict__ dwb,
    const int* __restrict__ topk_idx, const int* __restrict__ slot_of,
    const float* __restrict__ topk_w, float* __restrict__ out) {
    const int t = blockIdx.x;
    const int n = threadIdx.x * 4;
    float4 o = {0.f, 0.f, 0.f, 0.f};
#pragma unroll
    for (int k = 0; k < 4; ++k) {
        const int e = topk_idx[t * 4 + k];
        const int s = slot_of[t * 4 + k];
        const float wgt = topk_w[t * 4 + k];
        float4 d = *(const float4*)(dslot + (size_t)s * HD + n);
        float4 b = *(const float4*)(dwb + (size_t)e * HD + n);
        o.x += wgt * (d.x + b.x);
        o.y += wgt * (d.y + b.y);
        o.z += wgt * (d.z + b.z);
        o.w += wgt * (d.w + b.w);
    }
    *(float4*)(out + (size_t)t * HD + n) = o;
}

// ============ FALLBACK PATH (used only if ws too small) ============

__global__ __launch_bounds__(256) void gemm1_fb_kernel(
    const ushort* __restrict__ hb, const float* __restrict__ gup,
    const float* __restrict__ gub, const int* __restrict__ offsets,
    const int* __restrict__ token_list, ushort* __restrict__ act) {
    const int e = blockIdx.z;
    const int so = offsets[e];
    const int ne = offsets[e + 1] - so;
    const int row0 = blockIdx.y * 64;
    if (row0 >= ne) return;
    const int n0 = blockIdx.x * 64;
    __shared__ ushort Al[64][40];
    __shared__ ushort Bt[64][40];
    const int tid = threadIdx.x;
    const int lane = tid & 63;
    const int wave = tid >> 6;
    const int m = lane & 15;
    const int q = lane >> 4;
    const int ar = tid >> 2;
    const int ac = (tid & 3) * 8;
    int arow = row0 + ar; if (arow >= ne) arow = ne - 1;
    const int tok = token_list[so + arow];
    const ushort* aptr = hb + tok * HD + ac;
    const int bk = tid >> 3;
    const int bn = (tid & 7) * 8;
    const float* bptr = gup + (size_t)e * HD * TWO_I + (size_t)bk * TWO_I + n0 + bn;
    f32x4 acc[4] = {{0,0,0,0},{0,0,0,0},{0,0,0,0},{0,0,0,0}};
    for (int k0 = 0; k0 < HD; k0 += 32) {
        float4 av = *(const float4*)(aptr + k0);
        *(float4*)(&Al[ar][ac]) = av;
        const float* bp = bptr + (size_t)k0 * TWO_I;
        float4 b0 = *(const float4*)(bp);
        float4 b1 = *(const float4*)(bp + 4);
        Bt[bn + 0][bk] = f2bf(b0.x); Bt[bn + 1][bk] = f2bf(b0.y);
        Bt[bn + 2][bk] = f2bf(b0.z); Bt[bn + 3][bk] = f2bf(b0.w);
        Bt[bn + 4][bk] = f2bf(b1.x); Bt[bn + 5][bk] = f2bf(b1.y);
        Bt[bn + 6][bk] = f2bf(b1.z); Bt[bn + 7][bk] = f2bf(b1.w);
        __syncthreads();
        short8 af = *(const short8*)(&Al[wave * 16 + m][q * 8]);
#pragma unroll
        for (int c = 0; c < 4; ++c) {
            short8 bf = *(const short8*)(&Bt[c * 16 + m][q * 8]);
            acc[c] = __builtin_amdgcn_mfma_f32_16x16x32_bf16(af, bf, acc[c], 0, 0, 0);
        }
        __syncthreads();
    }
#pragma unroll
    for (int c = 0; c < 4; ++c) {
        const int n = n0 + c * 16 + m;
        const float bias = gub[e * TWO_I + n];
#pragma unroll
        for (int r = 0; r < 4; ++r) {
            const int grow = row0 + wave * 16 + q * 4 + r;
            float v = acc[c][r] + bias;
            float pv = __shfl_xor(v, 1);
            float gate = (m & 1) ? pv : v;
            float up   = (m & 1) ? v : pv;
            gate = fminf(gate, 7.0f);
            up = fminf(fmaxf(up, -7.0f), 7.0f);
            float glu = gate / (1.0f + __expf(-1.702f * gate));
            float a = (up + 1.0f) * glu;
            if (!(m & 1) && grow < ne)
                act[(size_t)(so + grow) * ID + (n >> 1)] = f2bf(a);
        }
    }
}

__global__ __launch_bounds__(256) void gemm2_fb_kernel(
    const ushort* __restrict__ act, const float* __restrict__ dwp,
    const float* __restrict__ dwb, const int* __restrict__ offsets,
    const int* __restrict__ token_list, const float* __restrict__ slot_w,
    float* __restrict__ out) {
    const int e = blockIdx.z;
    const int so = offsets[e];
    const int ne = offsets[e + 1] - so;
    const int row0 = blockIdx.y * 64;
    if (row0 >= ne) return;
    const int n0 = blockIdx.x * 64;
    __shared__ ushort Al[64][40];
    __shared__ ushort Bt[64][40];
    const int tid = threadIdx.x;
    const int lane = tid & 63;
    const int wave = tid >> 6;
    const int m = lane & 15;
    const int q = lane >> 4;
    const int ar = tid >> 2;
    const int ac = (tid & 3) * 8;
    int arow = row0 + ar; if (arow >= ne) arow = ne - 1;
    const ushort* aptr = act + (size_t)(so + arow) * ID + ac;
    const int bk = tid >> 3;
    const int bn = (tid & 7) * 8;
    const float* bptr = dwp + (size_t)e * ID * HD + (size_t)bk * HD + n0 + bn;
    f32x4 acc[4] = {{0,0,0,0},{0,0,0,0},{0,0,0,0},{0,0,0,0}};
    for (int k0 = 0; k0 < ID; k0 += 32) {
        float4 av = *(const float4*)(aptr + k0);
        *(float4*)(&Al[ar][ac]) = av;
        const float* bp = bptr + (size_t)k0 * HD;
        float4 b0 = *(const float4*)(bp);
        float4 b1 = *(const float4*)(bp + 4);
        Bt[bn + 0][bk] = f2bf(b0.x); Bt[bn + 1][bk] = f2bf(b0.y);
        Bt[bn + 2][bk] = f2bf(b0.z); Bt[bn + 3][bk] = f2bf(b0.w);
        Bt[bn + 4][bk] = f2bf(b1.x); Bt[bn + 5][bk] = f2bf(b1.y);
        Bt[bn + 6][bk] = f2bf(b1.z); Bt[bn + 7][bk] = f2bf(b1.w);
        __syncthreads();
        short8 af = *(const short8*)(&Al[wave * 16 + m][q * 8]);
#pragma unroll
        for (int c = 0; c < 4; ++c) {
            short8 bf = *(const short8*)(&Bt[c * 16 + m][q * 8]);
            acc[c] = __builtin_amdgcn_mfma_f32_16x16x32_bf16(af, bf, acc[c], 0, 0, 0);
        }
        __syncthreads();
    }
#pragma unroll
    for (int r = 0; r < 4; ++r) {
        const int grow = row0 + wave * 16 + q * 4 + r;
        if (grow < ne) {
            const int slot = so + grow;
            const int tok = token_list[slot];
            const float wgt = slot_w[slot];
#pragma unroll
            for (int c = 0; c < 4; ++c) {
                const int n = n0 + c * 16 + m;
                atomicAdd(&out[tok * HD + n], (acc[c][r] + dwb[e * HD + n]) * wgt);
            }
        }
    }
}

extern "C" void kernel_launch(void* const* d_in, const int* in_sizes, int n_in,
                              void* d_out, int out_size, void* d_ws, size_t ws_size,
                              hipStream_t stream) {
    const float* hs  = (const float*)d_in[0];
    const float* rw  = (const float*)d_in[1];
    const float* rb  = (const float*)d_in[2];
    const float* gup = (const float*)d_in[3];
    const float* gub = (const float*)d_in[4];
    const float* dwp = (const float*)d_in[5];
    const float* dwb = (const float*)d_in[6];

    float* out = (float*)d_out;                       // [2048,1024] fp32
    float* topk_w = out + (size_t)TOKENS * HD;        // [2048,4] fp32

    char* w = (char*)d_ws;
    int* counts     = (int*)(w + 0);
    int* offsets    = (int*)(w + 128);
    int* token_list = (int*)(w + 256);
    float* slot_w   = (float*)(w + 256 + 32768);
    int* topk_idx   = (int*)(w + 256 + 65536);
    int* slot_of    = (int*)(w + 256 + 98304);
    ushort* hb      = (ushort*)(w + ((size_t)1 << 20));           // 4 MB
    ushort* act     = (ushort*)(w + ((size_t)6 << 20));           // 8320x2048 bf16 (~34MB)
    ushort* gupT    = (ushort*)(w + ((size_t)41 << 20));          // 128 MB
    ushort* downT   = (ushort*)(w + ((size_t)169 << 20));         // 64 MB
    float* dslot    = (float*)(w + ((size_t)233 << 20));          // 8192x1024 fp32 (32 MB)
    const size_t need = (size_t)266 << 20;

    hipMemsetAsync(w, 0, 128, stream);

    router_kernel<<<512, 256, 0, stream>>>(hs, rw, rb, topk_w, topk_idx, counts, hb);
    scanbuild_kernel<<<1, 256, 0, stream>>>(counts, offsets, topk_idx, topk_w,
                                            token_list, slot_w, slot_of);

    if (ws_size >= need) {
        transpose_cvt2_kernel<<<dim3(64, 24, NEXP), 256, 0, stream>>>(
            gup, gupT, dwp, downT);
        gemm1_t_kernel<<<dim3(TWO_I / 128, TOKENS / 128, NEXP), 256, 0, stream>>>(
            hb, gupT, gub, offsets, token_list, act);
        gemm2_t_kernel<<<dim3(HD / 128, TOKENS / 128, NEXP), 256, 0, stream>>>(
            act, downT, offsets, dslot);
        combine_kernel<<<TOKENS, 256, 0, stream>>>(dslot, dwb, topk_idx, slot_of, topk_w, out);
    } else {
        // fallback: fp32 weights converted in-tile; atomic accumulate into zeroed out
        hipMemsetAsync(out, 0, (size_t)TOKENS * HD * sizeof(float), stream);
        gemm1_fb_kernel<<<dim3(TWO_I / 64, TOKENS / 64, NEXP), 256, 0, stream>>>(
            hb, gup, gub, offsets, token_list, act);
        gemm2_fb_kernel<<<dim3(HD / 64, TOKENS / 64, NEXP), 256, 0, stream>>>(
            act, dwp, dwb, offsets, token_list, slot_w, out);
    }
}